// Round 1
// baseline (131.338 us; speedup 1.0000x reference)
//
#include <hip/hip_runtime.h>
#include <math.h>

// Problem: B=4,S=2048,D=2048,E=64,K=2 -> tokens 8192, K-dim 2048, experts 64
#define NTOK 8192
#define DDIM 2048
#define NEXP 64
#define MT   16            // tokens per block
#define PSTR 68            // partial-buffer row stride (floats; 64+4 pad)

#define GATED_SZ (NTOK * NEXP)
#define IDX_OFF  GATED_SZ
#define VALS_OFF (GATED_SZ + NTOK * 2)

typedef _Float16 f16x8 __attribute__((ext_vector_type(8)));
typedef float    f32x4 __attribute__((ext_vector_type(4)));

// fp32 -> fp16 hi + 4096-scaled lo residual (identical split math to the
// old pack_b_kernel; verified absmax-stable in prior session).
static __device__ __forceinline__ void cvt_hilo(float4 v0, float4 v1,
                                                f16x8& h8, f16x8& l8)
{
    const float vv[8] = {v0.x, v0.y, v0.z, v0.w, v1.x, v1.y, v1.z, v1.w};
#pragma unroll
    for (int j = 0; j < 8; ++j) {
        const _Float16 hh = (_Float16)vv[j];
        h8[j] = hh;
        l8[j] = (_Float16)((vv[j] - (float)hh) * 4096.f);
    }
}

// ---------------------------------------------------------------------------
// Single fused kernel, BARRIER-FREE main loop. 512 blocks x 512 thr.
// Block = 16 tokens x all 64 experts. Wave w owns k-slice [w*256, w*256+256):
// no cross-wave sharing in the main loop -> no LDS staging, no per-chunk
// __syncthreads. A-fragments load directly from x (lane(q,m) reads
// x[tok=m][ks*32+q*8 ..+7], two float4, zero redundancy across waves).
// B-fragments load directly from W (lane(q,m) reads W[nt*16+m][ks*32+q*8..],
// two float4 = same bytes as the old Bh+Bl fp16 pair) and are hi/lo-split
// in registers -> the pack_b kernel + its launch + serialization vanish.
// logits = acc_hh + 2^-12 * acc_lo (x_lo, w_lo pre-scaled by 4096).
// One barrier total: 8 k-slice partials summed via LDS, then noise, top-2,
// softmax epilogue (unchanged from previous verified version).
// ---------------------------------------------------------------------------
__global__ __launch_bounds__(512, 4) void gate_kernel(
    const float* __restrict__ x,
    const float* __restrict__ W,
    const float* __restrict__ noise_w,
    const float* __restrict__ noise,
    float* __restrict__ out)
{
    __shared__ float cbuf[8][MT * PSTR];   // 34.8 KB: 8 k-slice partials

    const int tid  = threadIdx.x;
    const int lane = tid & 63;
    const int w    = __builtin_amdgcn_readfirstlane(tid >> 6);  // k-slice id
    const int tokBase = blockIdx.x * MT;

    const int q = lane >> 4;               // 0..3
    const int m = lane & 15;               // 0..15

    // wave w covers ks = w*8 + s, s = 0..7  (k = ks*32 + q*8 + j)
    const float* asrc = x + (size_t)(tokBase + m) * DDIM + (size_t)w * 256 + q * 8;
    const float* bsrc = W + (size_t)m * DDIM + (size_t)w * 256 + q * 8;

    f32x4 acc_hh[4], acc_lo[4];
#pragma unroll
    for (int nt = 0; nt < 4; ++nt) {
        acc_hh[nt] = (f32x4){0.f, 0.f, 0.f, 0.f};
        acc_lo[nt] = (f32x4){0.f, 0.f, 0.f, 0.f};
    }

#pragma unroll 2
    for (int s = 0; s < 8; ++s) {
        const size_t ko = (size_t)s * 32;

        // A-fragment: x rows = tokens, 8 consecutive fp32 per lane
        const float4 a0 = *(const float4*)(asrc + ko);
        const float4 a1 = *(const float4*)(asrc + ko + 4);
        f16x8 ah, al;
        cvt_hilo(a0, a1, ah, al);

#pragma unroll
        for (int nt = 0; nt < 4; ++nt) {
            // B-fragment: W row = expert nt*16+m, 8 consecutive fp32 per lane
            const float4 b0 = *(const float4*)(bsrc + (size_t)nt * 16 * DDIM + ko);
            const float4 b1 = *(const float4*)(bsrc + (size_t)nt * 16 * DDIM + ko + 4);
            f16x8 bh, bl;
            cvt_hilo(b0, b1, bh, bl);

            acc_hh[nt] = __builtin_amdgcn_mfma_f32_16x16x32_f16(ah, bh, acc_hh[nt], 0, 0, 0);
            acc_lo[nt] = __builtin_amdgcn_mfma_f32_16x16x32_f16(ah, bl, acc_lo[nt], 0, 0, 0);
            acc_lo[nt] = __builtin_amdgcn_mfma_f32_16x16x32_f16(al, bh, acc_lo[nt], 0, 0, 0);
        }
    }

    // combine hi/lo, write this wave's partial. C/D layout: col(e)=lane&15,
    // row(t)=q*4+r. Banks: stride 272B per q -> 2-way aliasing only (free).
#pragma unroll
    for (int nt = 0; nt < 4; ++nt) {
        const int e = nt * 16 + m;
#pragma unroll
        for (int r = 0; r < 4; ++r) {
            const int t = q * 4 + r;
            cbuf[w][t * PSTR + e] = acc_hh[nt][r] + acc_lo[nt][r] * (1.f / 4096.f);
        }
    }
    __syncthreads();   // the only barrier

    // Epilogue: wave w owns tokens w*2, w*2+1; lane = expert.
    const float nwv = noise_w[lane];
#pragma unroll
    for (int i = 0; i < 2; ++i) {
        const int t   = w * 2 + i;
        const int tok = tokBase + t;
        const int e   = lane;

        float v = 0.f;
#pragma unroll
        for (int p = 0; p < 8; ++p)
            v += cbuf[p][t * PSTR + e];
        v += noise[(size_t)tok * NEXP + e] * nwv;

        // top-1: butterfly max, lax.top_k tie-break (lower index wins)
        float m1 = v; int i1 = e;
#pragma unroll
        for (int sh = 32; sh > 0; sh >>= 1) {
            float ov = __shfl_xor(m1, sh, 64);
            int   oi = __shfl_xor(i1, sh, 64);
            if (ov > m1 || (ov == m1 && oi < i1)) { m1 = ov; i1 = oi; }
        }
        float vm = (e == i1) ? -INFINITY : v;
        float m2 = vm; int i2 = e;
#pragma unroll
        for (int sh = 32; sh > 0; sh >>= 1) {
            float ov = __shfl_xor(m2, sh, 64);
            int   oi = __shfl_xor(i2, sh, 64);
            if (ov > m2 || (ov == m2 && oi < i2)) { m2 = ov; i2 = oi; }
        }

        const float e2  = expf(m2 - m1);
        const float inv = 1.f / (1.f + e2);
        const float p1  = inv;
        const float p2  = e2 * inv;

        float gval = 0.f;
        if (e == i1) gval = p1;
        else if (e == i2) gval = p2;
        out[(size_t)tok * NEXP + e] = gval;

        if (lane == 0) {
            out[IDX_OFF  + tok * 2 + 0] = (float)i1;
            out[IDX_OFF  + tok * 2 + 1] = (float)i2;
            out[VALS_OFF + tok * 2 + 0] = m1;
            out[VALS_OFF + tok * 2 + 1] = m2;
        }
    }
}

extern "C" void kernel_launch(void* const* d_in, const int* in_sizes, int n_in,
                              void* d_out, int out_size, void* d_ws, size_t ws_size,
                              hipStream_t stream) {
    const float* x     = (const float*)d_in[0];
    const float* W     = (const float*)d_in[1];
    const float* nw    = (const float*)d_in[2];
    const float* noise = (const float*)d_in[3];
    // d_in[4] is k==2, hardcoded
    float* out = (float*)d_out;
    (void)d_ws; (void)ws_size;   // workspace no longer needed (pack fused)

    hipLaunchKernelGGL(gate_kernel, dim3(NTOK / MT), dim3(512), 0, stream,
                       x, W, nw, noise, out);
}

// Round 2
// 112.028 us; speedup vs baseline: 1.1724x; 1.1724x over previous
//
#include <hip/hip_runtime.h>
#include <math.h>

// Problem: B=4,S=2048,D=2048,E=64,K=2 -> tokens 8192, K-dim 2048, experts 64
#define NTOK 8192
#define DDIM 2048
#define NEXP 64
#define MT   16            // tokens per block
#define ASTR 136           // staging row stride in halves (128 + 8 pad; 16B-aligned rows)
#define CSTR 68            // partial-buffer row stride (floats)

#define GATED_SZ (NTOK * NEXP)
#define IDX_OFF  GATED_SZ
#define VALS_OFF (GATED_SZ + NTOK * 2)

#define NKSTEP (DDIM / 32)            // 64 MFMA k-steps
#define NTILE  (NEXP / 16)            // 4 n-tiles
#define BFRAG_HALVES ((size_t)NKSTEP * NTILE * 64 * 8)   // 131072 halves

typedef _Float16 f16x8 __attribute__((ext_vector_type(8)));
typedef float    f32x4 __attribute__((ext_vector_type(4)));

// ---------------------------------------------------------------------------
// Pack W [E=64][D=2048] into MFMA B-fragments (fp16 hi + 4096-scaled lo).
// Frag (ks, nt): lane holds B[k=ks*32+(lane>>4)*8+j][n=nt*16+(lane&15)].
// Layout: Bh[((ks*4+nt)*64+lane)*8 + j]. (Verified absmax-stable earlier.)
// ---------------------------------------------------------------------------
__global__ void pack_b_kernel(const float* __restrict__ W,
                              _Float16* __restrict__ Bh,
                              _Float16* __restrict__ Bl)
{
    const int tid  = blockIdx.x * blockDim.x + threadIdx.x;  // 0..16383
    const int lane = tid & 63;
    const int fid  = tid >> 6;
    const int ks   = fid >> 2;
    const int nt   = fid & 3;
    const int e    = nt * 16 + (lane & 15);
    const int k    = ks * 32 + (lane >> 4) * 8;
    const float* src = W + (size_t)e * DDIM + k;

    f16x8 hi, lo;
#pragma unroll
    for (int j = 0; j < 8; ++j) {
        const float v = src[j];
        const _Float16 h = (_Float16)v;
        hi[j] = h;
        lo[j] = (_Float16)((v - (float)h) * 4096.f);
    }
    *(f16x8*)(Bh + (size_t)tid * 8) = hi;
    *(f16x8*)(Bl + (size_t)tid * 8) = lo;
}

#define BFRAG(base, ks, nt) \
    (*(const f16x8*)((base) + ((((size_t)(ks)) * 4 + (nt)) * 64 + lane) * 8))

// fp32 -> fp16 hi + 4096-scaled lo residual (hi/lo sum is exact up to lo's
// own fp16 rounding; same split as pack_b).
static __device__ __forceinline__ void cvt_hilo(float4 v0, float4 v1,
                                                f16x8& h8, f16x8& l8)
{
    const float vv[8] = {v0.x, v0.y, v0.z, v0.w, v1.x, v1.y, v1.z, v1.w};
#pragma unroll
    for (int j = 0; j < 8; ++j) {
        const _Float16 hh = (_Float16)vv[j];
        h8[j] = hh;
        l8[j] = (_Float16)((vv[j] - (float)hh) * 4096.f);
    }
}

// ---------------------------------------------------------------------------
// Fused gate kernel, BARRIER-FREE main loop. 512 blocks x 512 thr (8 waves).
// Wave w owns k-slice [w*256, w*256+256) of all 16 tokens x all 64 experts:
// zero cross-wave sharing in the main loop. x is staged through a PER-WAVE
// PRIVATE LDS region (8.5 KB/wave) with fully coalesced global loads (each
// 16-lane group covers a contiguous 512B row segment); ds_write -> ds_read
// ordering within the wave is lgkmcnt-only -- NO s_barrier, so the next
// sub-chunk's global loads stay in flight across compute (round-0's barrier
// drained vmcnt(0) every chunk, serializing full HBM latency x8).
// B comes from the packed Bh/Bl fragments (coalesced 1KB/instr, cvt done
// once in pack_b). logits = acc_hh + 2^-12 * acc_lo.
// Two barriers total, protecting the cbuf alias before the top-2 epilogue.
// ---------------------------------------------------------------------------
__global__ __launch_bounds__(512, 4) void gate_kernel(
    const float* __restrict__ x,
    const _Float16* __restrict__ Bh,
    const _Float16* __restrict__ Bl,
    const float* __restrict__ noise_w,
    const float* __restrict__ noise,
    float* __restrict__ out)
{
    // per-wave staging: [hi|lo] x 16 rows x ASTR halves = 8704 B; x8 waves
    __shared__ _Float16 smem[8 * 2 * MT * ASTR];   // 69632 B -> 2 blocks/CU

    const int tid  = threadIdx.x;
    const int lane = tid & 63;
    const int w    = __builtin_amdgcn_readfirstlane(tid >> 6);  // k-slice id
    const int tokBase = blockIdx.x * MT;

    const int q = lane >> 4;               // 0..3
    const int m = lane & 15;               // 0..15

    _Float16* xs = smem + (size_t)w * (2 * MT * ASTR);  // hi at 0, lo at MT*ASTR

    // wave's x window: 16 tokens x 256 k starting at w*256
    const float* xw = x + (size_t)tokBase * DDIM + (size_t)w * 256;

    f32x4 acc_hh[4], acc_lo[4];
#pragma unroll
    for (int nt = 0; nt < 4; ++nt) {
        acc_hh[nt] = (f32x4){0.f, 0.f, 0.f, 0.f};
        acc_lo[nt] = (f32x4){0.f, 0.f, 0.f, 0.f};
    }

    // Sub-chunk = 128 k. Piece p: lane covers row p*4+q, floats m*8..m*8+7.
    // Per instruction lanes 0-15 span one contiguous 512B row segment.
#define LOADSUB(sc)                                                          \
    _Pragma("unroll")                                                        \
    for (int p = 0; p < 4; ++p) {                                            \
        const float* src = xw + (size_t)(p * 4 + q) * DDIM + (sc) * 128 + m * 8; \
        s0[p] = *(const float4*)(src);                                       \
        s1[p] = *(const float4*)(src + 4);                                   \
    }

#define STAGESUB()                                                           \
    _Pragma("unroll")                                                        \
    for (int p = 0; p < 4; ++p) {                                            \
        f16x8 h8, l8;                                                        \
        cvt_hilo(s0[p], s1[p], h8, l8);                                      \
        const int off = (p * 4 + q) * ASTR + m * 8;                          \
        *(f16x8*)&xs[off] = h8;                                              \
        *(f16x8*)&xs[MT * ASTR + off] = l8;                                  \
    }

    // k-step stp within sub-chunk sc: global ks = w*8 + sc*4 + stp
#define COMPUTESUB(sc)                                                       \
    _Pragma("unroll")                                                        \
    for (int stp = 0; stp < 4; ++stp) {                                      \
        const int ks = w * 8 + (sc) * 4 + stp;                               \
        const f16x8 ah = *(const f16x8*)&xs[m * ASTR + stp * 32 + q * 8];    \
        const f16x8 al = *(const f16x8*)&xs[MT * ASTR + m * ASTR + stp * 32 + q * 8]; \
        _Pragma("unroll")                                                    \
        for (int nt = 0; nt < 4; ++nt) {                                     \
            const f16x8 bh = BFRAG(Bh, ks, nt);                              \
            const f16x8 bl = BFRAG(Bl, ks, nt);                              \
            acc_hh[nt] = __builtin_amdgcn_mfma_f32_16x16x32_f16(ah, bh, acc_hh[nt], 0, 0, 0); \
            acc_lo[nt] = __builtin_amdgcn_mfma_f32_16x16x32_f16(ah, bl, acc_lo[nt], 0, 0, 0); \
            acc_lo[nt] = __builtin_amdgcn_mfma_f32_16x16x32_f16(al, bh, acc_lo[nt], 0, 0, 0); \
        }                                                                    \
    }

    float4 s0[4], s1[4];
    LOADSUB(0)          // issue sub-chunk 0 loads
    STAGESUB()          // cvt + ds_write sc0 (vmcnt wait happens here)
    LOADSUB(1)          // issue sub-chunk 1 loads; in flight across compute
    COMPUTESUB(0)       // lgkmcnt-ordered ds_read + packed-B loads + MFMA
    STAGESUB()          // sc1 (compiler orders vs sc0 reads via lgkmcnt)
    COMPUTESUB(1)

#undef LOADSUB
#undef STAGESUB
#undef COMPUTESUB

    // ---- epilogue: 8 k-slice partials -> cbuf (aliases staging LDS) ----
    __syncthreads();    // all waves done reading their staging regions
    float* cbuf = (float*)smem;   // [8 partials][16 tokens][CSTR] = 34816 B

    // C/D layout: col(e)=lane&15, row(t)=q*4+r
#pragma unroll
    for (int nt = 0; nt < 4; ++nt) {
        const int e = nt * 16 + m;
#pragma unroll
        for (int r = 0; r < 4; ++r) {
            const int t = q * 4 + r;
            cbuf[((w * MT) + t) * CSTR + e] = acc_hh[nt][r] + acc_lo[nt][r] * (1.f / 4096.f);
        }
    }
    __syncthreads();

    // Epilogue: wave w owns tokens w*2, w*2+1; lane = expert.
    const float nwv = noise_w[lane];
#pragma unroll
    for (int i = 0; i < 2; ++i) {
        const int t   = w * 2 + i;
        const int tok = tokBase + t;
        const int e   = lane;

        float v = 0.f;
#pragma unroll
        for (int p = 0; p < 8; ++p)
            v += cbuf[((p * MT) + t) * CSTR + e];
        v += noise[(size_t)tok * NEXP + e] * nwv;

        // top-1: butterfly max, lax.top_k tie-break (lower index wins)
        float m1 = v; int i1 = e;
#pragma unroll
        for (int sh = 32; sh > 0; sh >>= 1) {
            float ov = __shfl_xor(m1, sh, 64);
            int   oi = __shfl_xor(i1, sh, 64);
            if (ov > m1 || (ov == m1 && oi < i1)) { m1 = ov; i1 = oi; }
        }
        float vm = (e == i1) ? -INFINITY : v;
        float m2 = vm; int i2 = e;
#pragma unroll
        for (int sh = 32; sh > 0; sh >>= 1) {
            float ov = __shfl_xor(m2, sh, 64);
            int   oi = __shfl_xor(i2, sh, 64);
            if (ov > m2 || (ov == m2 && oi < i2)) { m2 = ov; i2 = oi; }
        }

        const float e2  = expf(m2 - m1);
        const float inv = 1.f / (1.f + e2);
        const float p1  = inv;
        const float p2  = e2 * inv;

        float gval = 0.f;
        if (e == i1) gval = p1;
        else if (e == i2) gval = p2;
        out[(size_t)tok * NEXP + e] = gval;

        if (lane == 0) {
            out[IDX_OFF  + tok * 2 + 0] = (float)i1;
            out[IDX_OFF  + tok * 2 + 1] = (float)i2;
            out[VALS_OFF + tok * 2 + 0] = m1;
            out[VALS_OFF + tok * 2 + 1] = m2;
        }
    }
}

extern "C" void kernel_launch(void* const* d_in, const int* in_sizes, int n_in,
                              void* d_out, int out_size, void* d_ws, size_t ws_size,
                              hipStream_t stream) {
    const float* x     = (const float*)d_in[0];
    const float* W     = (const float*)d_in[1];
    const float* nw    = (const float*)d_in[2];
    const float* noise = (const float*)d_in[3];
    // d_in[4] is k==2, hardcoded
    float* out = (float*)d_out;

    _Float16* Bh = (_Float16*)d_ws;                 // 256 KB
    _Float16* Bl = Bh + BFRAG_HALVES;               // 256 KB

    hipLaunchKernelGGL(pack_b_kernel, dim3(64), dim3(256), 0, stream, W, Bh, Bl);

    hipLaunchKernelGGL(gate_kernel, dim3(NTOK / MT), dim3(512), 0, stream,
                       x, Bh, Bl, nw, noise, out);
}